// Round 2
// baseline (321.084 us; speedup 1.0000x reference)
//
#include <hip/hip_runtime.h>

typedef __attribute__((ext_vector_type(8))) short short8;
typedef __attribute__((ext_vector_type(4))) float f32x4;

#define D_ 256
#define QT_V 3000
#define QR_V 216
#define QO_V 1
#define QPT 3008          // padded head-t rows
#define QPR 224           // padded head-r rows
#define QPO 96            // padded head-o rows
#define QPTOT 3328        // 26 * 128
#define NSPLIT 8
#define VPAD 32           // vsum tail padding per head
#define SCALE 0.09016844005556021f   /* log2(e)/16 */
#define LDS_STRIDE 264    /* ushorts per LDS row: 256 + 8 pad (528B = 33*16B) */

__device__ __forceinline__ unsigned short f2bf(float f) {
    union { float f; unsigned int i; } u; u.f = f;
    unsigned int i = u.i + 0x7fffu + ((u.i >> 16) & 1u);
    return (unsigned short)(i >> 16);
}

// WqT[q][c] = SCALE * sum_d Wk[c][d] * Q[q][d]  (f32 inputs, bf16 out);
// zero for padded rows. grid.x = nrows_padded/8, block = 256 (thread = c)
__global__ __launch_bounds__(256) void prep_wq(
    const float* __restrict__ Q,
    const float* __restrict__ Wk,
    unsigned short* __restrict__ out,
    int nvalid)
{
    int c = threadIdx.x;
    int q0 = blockIdx.x * 8;
    float acc[8];
#pragma unroll
    for (int r = 0; r < 8; ++r) acc[r] = 0.f;
    const float* wr = Wk + (size_t)c * D_;
    for (int d = 0; d < D_; d += 4) {
        float4 wv = *(const float4*)(wr + d);
#pragma unroll
        for (int r = 0; r < 8; ++r) {
            int q = q0 + r;
            if (q < nvalid) {
                float4 qv = *(const float4*)(Q + (size_t)q * D_ + d);
                acc[r] += wv.x * qv.x + wv.y * qv.y + wv.z * qv.z + wv.w * qv.w;
            }
        }
    }
#pragma unroll
    for (int r = 0; r < 8; ++r) {
        int q = q0 + r;
        float v = (q < nvalid) ? acc[r] * SCALE : 0.f;
        out[(size_t)(q0 + r) * D_ + c] = f2bf(v);
    }
}

// wvsum[h*256+c] = sum_d Wv_h[c][d] (f32); also zero vsum tail pads.
__global__ __launch_bounds__(256) void prep_wvsum(
    const float* __restrict__ Wv0,
    const float* __restrict__ Wv1,
    const float* __restrict__ Wv2,
    float* __restrict__ wvsum,
    float* __restrict__ vsum, int N)
{
    int t = blockIdx.x * 256 + threadIdx.x;
    if (t < 768) {
        int h = t >> 8, c = t & 255;
        const float* Wv = (h == 0) ? Wv0 : ((h == 1) ? Wv1 : Wv2);
        const float* row = Wv + (size_t)c * D_;
        float s = 0.f;
        for (int d = 0; d < D_; d += 4) {
            float4 wv = *(const float4*)(row + d);
            s += wv.x + wv.y + wv.z + wv.w;
        }
        wvsum[t] = s;
    }
    if (t < 3 * VPAD) {
        int h = t / VPAD, i = t % VPAD;
        vsum[(size_t)h * (N + VPAD) + N + i] = 0.f;
    }
}

// Convert feat f32 -> bf16 (for MFMA staging) and compute the three
// vsum dot-products in f32. One wave per row, 4 rows/block.
__global__ __launch_bounds__(256) void conv_feat(
    const float* __restrict__ feat,
    const float* __restrict__ wvsum,
    unsigned short* __restrict__ featb,
    float* __restrict__ vsum, int N)
{
    int row = blockIdx.x * 4 + (threadIdx.x >> 6);
    int lane = threadIdx.x & 63;
    if (row >= N) return;
    float4 fv = *(const float4*)(feat + (size_t)row * D_ + lane * 4);
    ushort4 ob;
    ob.x = f2bf(fv.x); ob.y = f2bf(fv.y); ob.z = f2bf(fv.z); ob.w = f2bf(fv.w);
    *(ushort4*)(featb + (size_t)row * D_ + lane * 4) = ob;
    float p0, p1, p2;
    {
        const float* w = wvsum + lane * 4;
        float4 w0 = *(const float4*)(w);
        float4 w1 = *(const float4*)(w + 256);
        float4 w2 = *(const float4*)(w + 512);
        p0 = fv.x * w0.x + fv.y * w0.y + fv.z * w0.z + fv.w * w0.w;
        p1 = fv.x * w1.x + fv.y * w1.y + fv.z * w1.z + fv.w * w1.w;
        p2 = fv.x * w2.x + fv.y * w2.y + fv.z * w2.z + fv.w * w2.w;
    }
#pragma unroll
    for (int off = 32; off >= 1; off >>= 1) {
        p0 += __shfl_xor(p0, off);
        p1 += __shfl_xor(p1, off);
        p2 += __shfl_xor(p2, off);
    }
    if (lane == 0) {
        vsum[0 * (size_t)(N + VPAD) + row] = p0;
        vsum[1 * (size_t)(N + VPAD) + row] = p1;
        vsum[2 * (size_t)(N + VPAD) + row] = p2;
    }
}

// Fused scores-GEMM + online softmax-weighted mean. grid (NSPLIT, QPTOT/128, B)
__global__ __launch_bounds__(256) void attn_main(
    const unsigned short* __restrict__ feat,
    const int* __restrict__ npts,
    const unsigned short* __restrict__ WqT,
    const float* __restrict__ vsum,
    float* __restrict__ partials,
    int N)
{
    __shared__ __align__(16) unsigned short lds[32 * LDS_STRIDE];

    const float NEG = -__builtin_inff();
    int b = blockIdx.z, qblock = blockIdx.y, chunk = blockIdx.x;
    int tid = (int)threadIdx.x;
    int wave = tid >> 6, lane = tid & 63;
    int col = lane & 15, quad = lane >> 4;

    int qp0 = qblock * 128 + wave * 32;   // head boundaries (3008, 3232) are 32-aligned
    int h = (qp0 < QPT) ? 0 : ((qp0 < QPT + QPR) ? 1 : 2);
    const float* vs = vsum + (size_t)h * (N + VPAD);

    int start = 0;
#pragma unroll 1
    for (int i = 0; i < b; ++i) start += npts[i];
    int end = start + npts[b];
    if (end > N) end = N;
    if (start > end) start = end;
    int len = ((end - start + NSPLIT - 1) / NSPLIT + 15) & ~15;
    int cs = start + chunk * len;
    int ce = cs + len; if (ce > end) ce = end;

    // B fragments for 2 query tiles, kept in registers for the whole kernel
    short8 bfrag[2][8];
#pragma unroll
    for (int qt = 0; qt < 2; ++qt) {
        const unsigned short* wr = WqT + (size_t)(qp0 + qt * 16 + col) * D_ + quad * 8;
#pragma unroll
        for (int kk = 0; kk < 8; ++kk)
            bfrag[qt][kk] = *(const short8*)(wr + kk * 32);
    }

    float m0 = NEG, den0 = 0.f, num0 = 0.f;
    float m1 = NEG, den1 = 0.f, num1 = 0.f;

    int srow = tid >> 3;     // 0..31
    int schunk = tid & 7;    // 64B chunk within row

    for (int n0 = cs; n0 < ce; n0 += 32) {
        // ---- stage 32 rows x 256 bf16 into LDS ----
        int gr = n0 + srow; if (gr > end - 1) gr = end - 1;
        const uint4* gp = (const uint4*)(feat + (size_t)gr * D_ + schunk * 32);
        uint4 t0 = gp[0], t1 = gp[1], t2 = gp[2], t3 = gp[3];
        __syncthreads();
        uint4* lp = (uint4*)(lds + srow * LDS_STRIDE + schunk * 32);
        lp[0] = t0; lp[1] = t1; lp[2] = t2; lp[3] = t3;
        __syncthreads();

        // ---- MFMA: 2 row-tiles x 2 q-tiles over K=256 ----
        f32x4 acc00 = {0.f,0.f,0.f,0.f}, acc01 = {0.f,0.f,0.f,0.f};
        f32x4 acc10 = {0.f,0.f,0.f,0.f}, acc11 = {0.f,0.f,0.f,0.f};
#pragma unroll
        for (int kk = 0; kk < 8; ++kk) {
            short8 a0 = *(const short8*)(lds + col * LDS_STRIDE + quad * 8 + kk * 32);
            short8 a1 = *(const short8*)(lds + (16 + col) * LDS_STRIDE + quad * 8 + kk * 32);
            acc00 = __builtin_amdgcn_mfma_f32_16x16x32_bf16(a0, bfrag[0][kk], acc00, 0, 0, 0);
            acc10 = __builtin_amdgcn_mfma_f32_16x16x32_bf16(a0, bfrag[1][kk], acc10, 0, 0, 0);
            acc01 = __builtin_amdgcn_mfma_f32_16x16x32_bf16(a1, bfrag[0][kk], acc01, 0, 0, 0);
            acc11 = __builtin_amdgcn_mfma_f32_16x16x32_bf16(a1, bfrag[1][kk], acc11, 0, 0, 0);
        }

        // ---- online softmax update ----
        int rb = n0 + quad * 4;                  // rowtile0 rows rb..rb+3, rowtile1 +16
        f32x4 vsv0 = *(const f32x4*)(vs + rb);
        f32x4 vsv1 = *(const f32x4*)(vs + rb + 16);
        bool va[4], vb[4];
#pragma unroll
        for (int r = 0; r < 4; ++r) { va[r] = (rb + r) < ce; vb[r] = (rb + 16 + r) < ce; }

        // qtile 0
        {
            float tm = NEG;
#pragma unroll
            for (int r = 0; r < 4; ++r) {
                tm = fmaxf(tm, va[r] ? acc00[r] : NEG);
                tm = fmaxf(tm, vb[r] ? acc01[r] : NEG);
            }
            tm = fmaxf(tm, __shfl_xor(tm, 16));
            tm = fmaxf(tm, __shfl_xor(tm, 32));
            float nm = fmaxf(m0, tm);
            float al = __builtin_amdgcn_exp2f(m0 - nm);
            den0 *= al; num0 *= al;
#pragma unroll
            for (int r = 0; r < 4; ++r) {
                float e = va[r] ? __builtin_amdgcn_exp2f(acc00[r] - nm) : 0.f;
                den0 += e; num0 += e * vsv0[r];
                float e2 = vb[r] ? __builtin_amdgcn_exp2f(acc01[r] - nm) : 0.f;
                den0 += e2; num0 += e2 * vsv1[r];
            }
            m0 = nm;
        }
        // qtile 1
        {
            float tm = NEG;
#pragma unroll
            for (int r = 0; r < 4; ++r) {
                tm = fmaxf(tm, va[r] ? acc10[r] : NEG);
                tm = fmaxf(tm, vb[r] ? acc11[r] : NEG);
            }
            tm = fmaxf(tm, __shfl_xor(tm, 16));
            tm = fmaxf(tm, __shfl_xor(tm, 32));
            float nm = fmaxf(m1, tm);
            float al = __builtin_amdgcn_exp2f(m1 - nm);
            den1 *= al; num1 *= al;
#pragma unroll
            for (int r = 0; r < 4; ++r) {
                float e = va[r] ? __builtin_amdgcn_exp2f(acc10[r] - nm) : 0.f;
                den1 += e; num1 += e * vsv0[r];
                float e2 = vb[r] ? __builtin_amdgcn_exp2f(acc11[r] - nm) : 0.f;
                den1 += e2; num1 += e2 * vsv1[r];
            }
            m1 = nm;
        }
    }

    // cross-quad reduce (m already quad-uniform)
    den0 += __shfl_xor(den0, 16); den0 += __shfl_xor(den0, 32);
    num0 += __shfl_xor(num0, 16); num0 += __shfl_xor(num0, 32);
    den1 += __shfl_xor(den1, 16); den1 += __shfl_xor(den1, 32);
    num1 += __shfl_xor(num1, 16); num1 += __shfl_xor(num1, 32);

    if (quad == 0) {
        size_t base = ((size_t)b * QPTOT + (qp0 + col)) * NSPLIT + chunk;
        float* p0 = partials + base * 3;
        p0[0] = m0; p0[1] = den0; p0[2] = num0;
        float* p1 = partials + (base + (size_t)16 * NSPLIT) * 3;
        p1[0] = m1; p1[1] = den1; p1[2] = num1;
    }
}

// Combine NSPLIT partials per (b, qp) and scatter to output (f32).
__global__ __launch_bounds__(256) void combine_k(
    const float* __restrict__ partials,
    float* __restrict__ out, int Bn)
{
    int gid = blockIdx.x * 256 + threadIdx.x;
    int total = Bn * QPTOT;
    if (gid >= total) return;
    int b = gid / QPTOT, qp = gid - b * QPTOT;
    const float* p = partials + (size_t)gid * NSPLIT * 3;
    const float NEG = -__builtin_inff();
    float M = NEG;
#pragma unroll
    for (int c = 0; c < NSPLIT; ++c) M = fmaxf(M, p[c * 3]);
    float den = 0.f, num = 0.f;
    if (M > NEG) {
#pragma unroll
        for (int c = 0; c < NSPLIT; ++c) {
            float a = __builtin_amdgcn_exp2f(p[c * 3] - M);
            den += p[c * 3 + 1] * a;
            num += p[c * 3 + 2] * a;
        }
    }
    float val = (den > 0.f) ? (num / den) : 0.f;
    int oidx = -1;
    if (qp < QPT) {
        if (qp < QT_V) oidx = b * QT_V + qp;
    } else if (qp < QPT + QPR) {
        int q = qp - QPT;
        if (q < QR_V) oidx = Bn * QT_V + b * QR_V + q;
    } else {
        int q = qp - QPT - QPR;
        if (q < QO_V) oidx = Bn * (QT_V + QR_V) + b;
    }
    if (oidx >= 0) out[oidx] = val;
}

extern "C" void kernel_launch(void* const* d_in, const int* in_sizes, int n_in,
                              void* d_out, int out_size, void* d_ws, size_t ws_size,
                              hipStream_t stream)
{
    const float* feat = (const float*)d_in[0];
    const int* npts   = (const int*)d_in[1];
    const float* q_t  = (const float*)d_in[2];
    const float* wk_t = (const float*)d_in[3];
    const float* wv_t = (const float*)d_in[4];
    const float* q_r  = (const float*)d_in[5];
    const float* wk_r = (const float*)d_in[6];
    const float* wv_r = (const float*)d_in[7];
    const float* q_o  = (const float*)d_in[8];
    const float* wk_o = (const float*)d_in[9];
    const float* wv_o = (const float*)d_in[10];

    int N  = in_sizes[0] / D_;
    int Bn = in_sizes[1];

    char* ws = (char*)d_ws;
    size_t off = 0;
    unsigned short* WqT = (unsigned short*)(ws + off);
    off += (size_t)QPTOT * D_ * sizeof(unsigned short);
    off = (off + 255) & ~(size_t)255;
    unsigned short* featb = (unsigned short*)(ws + off);
    off += (size_t)N * D_ * sizeof(unsigned short);
    off = (off + 255) & ~(size_t)255;
    float* wvsum = (float*)(ws + off);
    off += 3 * D_ * sizeof(float);
    off = (off + 255) & ~(size_t)255;
    float* vsum = (float*)(ws + off);
    off += (size_t)3 * (N + VPAD) * sizeof(float);
    off = (off + 255) & ~(size_t)255;
    float* partials = (float*)(ws + off);
    off += (size_t)Bn * QPTOT * NSPLIT * 3 * sizeof(float);
    (void)ws_size;

    prep_wq<<<QPT / 8, 256, 0, stream>>>(q_t, wk_t, WqT, QT_V);
    prep_wq<<<QPR / 8, 256, 0, stream>>>(q_r, wk_r, WqT + (size_t)QPT * D_, QR_V);
    prep_wq<<<QPO / 8, 256, 0, stream>>>(q_o, wk_o, WqT + (size_t)(QPT + QPR) * D_, QO_V);
    prep_wvsum<<<3, 256, 0, stream>>>(wv_t, wv_r, wv_o, wvsum, vsum, N);
    conv_feat<<<(N + 3) / 4, 256, 0, stream>>>(feat, wvsum, featb, vsum, N);

    dim3 grid(NSPLIT, QPTOT / 128, Bn);
    attn_main<<<grid, 256, 0, stream>>>(featb, npts, WqT, vsum, partials, N);

    int total = Bn * QPTOT;
    combine_k<<<(total + 255) / 256, 256, 0, stream>>>(partials, (float*)d_out, Bn);
}

// Round 3
// 226.989 us; speedup vs baseline: 1.4145x; 1.4145x over previous
//
#include <hip/hip_runtime.h>

typedef __attribute__((ext_vector_type(8))) short short8;
typedef __attribute__((ext_vector_type(4))) float f32x4;
typedef unsigned int u32;

#define D_ 256
#define QT_V 3000
#define QR_V 216
#define QO_V 1
#define QPT 3008          // padded head-t rows
#define QPR 224           // padded head-r rows
#define QPO 96            // padded head-o rows
#define QPTOT 3328        // 26 * 128
#define NSPLIT 8
#define VPAD 32           // vsum tail padding per head
#define SCALE 0.09016844005556021f   /* log2(e)/16 */
#define TILE_US 8192      /* ushorts per 32-row x 256-col bf16 tile */

__device__ __forceinline__ unsigned short f2bf(float f) {
    union { float f; unsigned int i; } u; u.f = f;
    unsigned int i = u.i + 0x7fffu + ((u.i >> 16) & 1u);
    return (unsigned short)(i >> 16);
}

// async 16B/lane global->LDS; l must be wave-uniform, lanes land at l + lane*16
__device__ __forceinline__ void async_cp16(const unsigned short* g, unsigned short* l) {
    __builtin_amdgcn_global_load_lds((const __attribute__((address_space(1))) u32*)g,
                                     (__attribute__((address_space(3))) u32*)l, 16, 0, 0);
}

// ---------------- prep_all: WqT for 3 heads + wvsum + vsum pad zeroing -------
// blocks 0..415: WqT rows (8 per block). block 416: wvsum + pads.
#define WQ_BLKS 416
__global__ __launch_bounds__(256) void prep_all(
    const float* __restrict__ q_t, const float* __restrict__ wk_t,
    const float* __restrict__ q_r, const float* __restrict__ wk_r,
    const float* __restrict__ q_o, const float* __restrict__ wk_o,
    const float* __restrict__ wv_t, const float* __restrict__ wv_r,
    const float* __restrict__ wv_o,
    unsigned short* __restrict__ WqT,
    float* __restrict__ wvsum, float* __restrict__ vsum, int N)
{
    int blk = blockIdx.x;
    int c = threadIdx.x;
    if (blk == WQ_BLKS) {
        // wvsum[h*256+c] = row-sum of Wv_h row c
#pragma unroll
        for (int h = 0; h < 3; ++h) {
            const float* Wv = (h == 0) ? wv_t : ((h == 1) ? wv_r : wv_o);
            const float* row = Wv + (size_t)c * D_;
            float s = 0.f;
            for (int d = 0; d < D_; d += 4) {
                float4 wv = *(const float4*)(row + d);
                s += wv.x + wv.y + wv.z + wv.w;
            }
            wvsum[h * 256 + c] = s;
        }
        if (c < 3 * VPAD) {
            int h = c / VPAD, i = c % VPAD;
            vsum[(size_t)h * (N + VPAD) + N + i] = 0.f;
        }
        return;
    }
    const float *Q, *Wk; int nvalid, q0; size_t outbase;
    if (blk < 376)      { Q = q_t; Wk = wk_t; nvalid = QT_V; outbase = 0;                      q0 = blk * 8; }
    else if (blk < 404) { Q = q_r; Wk = wk_r; nvalid = QR_V; outbase = (size_t)QPT * D_;       q0 = (blk - 376) * 8; }
    else                { Q = q_o; Wk = wk_o; nvalid = QO_V; outbase = (size_t)(QPT + QPR) * D_; q0 = (blk - 404) * 8; }

    float acc[8];
#pragma unroll
    for (int r = 0; r < 8; ++r) acc[r] = 0.f;
    const float* wr = Wk + (size_t)c * D_;
    for (int d = 0; d < D_; d += 4) {
        float4 wv = *(const float4*)(wr + d);
#pragma unroll
        for (int r = 0; r < 8; ++r) {
            if (q0 + r < nvalid) {
                float4 qv = *(const float4*)(Q + (size_t)(q0 + r) * D_ + d);
                acc[r] += wv.x * qv.x + wv.y * qv.y + wv.z * qv.z + wv.w * qv.w;
            }
        }
    }
#pragma unroll
    for (int r = 0; r < 8; ++r) {
        float v = (q0 + r < nvalid) ? acc[r] * SCALE : 0.f;
        WqT[outbase + (size_t)(q0 + r) * D_ + c] = f2bf(v);
    }
}

// ---------------- fuse_feat: swizzle feat f32 -> bf16 A-frag tiles + vsum ----
// one block per 32-row tile; wave w handles combos c=4w..4w+3 (kk=c>>1, sub=c&1)
__global__ __launch_bounds__(256) void fuse_feat(
    const float* __restrict__ feat,
    const float* __restrict__ wvsum,
    unsigned short* __restrict__ featb,
    float* __restrict__ vsum, int N)
{
    __shared__ float part[4][2][16][3];
    int t = blockIdx.x;
    int tid = (int)threadIdx.x, wave = tid >> 6, lane = tid & 63;
    float p[2][3] = {{0.f,0.f,0.f},{0.f,0.f,0.f}};
#pragma unroll
    for (int i = 0; i < 4; ++i) {
        int cmb = wave * 4 + i;
        int kk = cmb >> 1, sub = cmb & 1;
        int row = t * 32 + sub * 16 + (lane & 15);
        int k0 = ((lane >> 4) & 3) * 8 + kk * 32;
        float f[8];
        if (row < N) {
            float4 x = *(const float4*)(feat + (size_t)row * D_ + k0);
            float4 y = *(const float4*)(feat + (size_t)row * D_ + k0 + 4);
            f[0]=x.x; f[1]=x.y; f[2]=x.z; f[3]=x.w;
            f[4]=y.x; f[5]=y.y; f[6]=y.z; f[7]=y.w;
        } else {
#pragma unroll
            for (int j = 0; j < 8; ++j) f[j] = 0.f;
        }
        short8 ob;
#pragma unroll
        for (int j = 0; j < 8; ++j) ob[j] = (short)f2bf(f[j]);
        *(short8*)(featb + (size_t)t * TILE_US + cmb * 512 + lane * 8) = ob;
#pragma unroll
        for (int h = 0; h < 3; ++h) {
            const float* w = wvsum + h * 256 + k0;
            float s = f[0]*w[0] + f[1]*w[1] + f[2]*w[2] + f[3]*w[3]
                    + f[4]*w[4] + f[5]*w[5] + f[6]*w[6] + f[7]*w[7];
            p[sub][h] += s;
        }
    }
#pragma unroll
    for (int sub = 0; sub < 2; ++sub)
#pragma unroll
        for (int h = 0; h < 3; ++h) {
            float v = p[sub][h];
            v += __shfl_xor(v, 16);
            v += __shfl_xor(v, 32);
            p[sub][h] = v;
        }
    if (lane < 16) {
#pragma unroll
        for (int sub = 0; sub < 2; ++sub)
#pragma unroll
            for (int h = 0; h < 3; ++h)
                part[wave][sub][lane][h] = p[sub][h];
    }
    __syncthreads();
    if (tid < 96) {
        int row = tid & 31, h = tid >> 5;
        float s = part[0][row >> 4][row & 15][h] + part[1][row >> 4][row & 15][h]
                + part[2][row >> 4][row & 15][h] + part[3][row >> 4][row & 15][h];
        int gr = t * 32 + row;
        if (gr < N) vsum[(size_t)h * (N + VPAD) + gr] = s;
    }
}

// ---------------- attn_main v2: async-staged tiles, maskless softmax ---------
// grid (NSPLIT, QPTOT/128, B), block 256 (4 waves x 32 q-cols)
__global__ __launch_bounds__(256, 4) void attn_main(
    const unsigned short* __restrict__ featb,
    const int* __restrict__ npts,
    const unsigned short* __restrict__ WqT,
    const float* __restrict__ vsum,
    float* __restrict__ partials, int N)
{
    __shared__ __align__(16) unsigned short lds[2][TILE_US];
    int b = blockIdx.z, qblock = blockIdx.y, chunk = blockIdx.x;
    int tid = (int)threadIdx.x;
    int wave = tid >> 6, lane = tid & 63;
    int col = lane & 15, quad = lane >> 4;

    int qp0 = qblock * 128 + wave * 32;
    int h = (qp0 < QPT) ? 0 : ((qp0 < QPT + QPR) ? 1 : 2);
    const float* vs = vsum + (size_t)h * (N + VPAD);

    int start = 0;
#pragma unroll 1
    for (int i = 0; i < b; ++i) start += npts[i];
    int end = start + npts[b];
    if (end > N) end = N;
    if (start < 0) start = 0;
    if (start > end) start = end;
    int bt0 = start >> 5, bt1 = (end + 31) >> 5;
    int ntc = (bt1 - bt0 + NSPLIT - 1) / NSPLIT;
    int ta = bt0 + chunk * ntc;
    int tb = ta + ntc; if (tb > bt1) tb = bt1;

    // B fragments (2 q-tiles x K=256) resident in registers
    short8 bfrag[2][8];
#pragma unroll
    for (int qt = 0; qt < 2; ++qt) {
        const unsigned short* wr = WqT + (size_t)(qp0 + qt * 16 + col) * D_ + quad * 8;
#pragma unroll
        for (int kk = 0; kk < 8; ++kk)
            bfrag[qt][kk] = *(const short8*)(wr + kk * 32);
    }

    float den0 = 0.f, num0 = 0.f, den1 = 0.f, num1 = 0.f;
    int p = 0;
    if (ta < tb) {
        // prefetch first tile: this wave stages its 4 frag-blocks
        const unsigned short* g = featb + (size_t)ta * TILE_US + (wave * 4) * 512 + lane * 8;
#pragma unroll
        for (int i = 0; i < 4; ++i)
            async_cp16(g + i * 512, &lds[0][(wave * 4 + i) * 512]);
    }
#pragma unroll 1
    for (int t = ta; t < tb; ++t) {
        __syncthreads();   // drains this wave's async copies into lds[p]
        if (t + 1 < tb) {
            const unsigned short* g = featb + (size_t)(t + 1) * TILE_US + (wave * 4) * 512 + lane * 8;
#pragma unroll
            for (int i = 0; i < 4; ++i)
                async_cp16(g + i * 512, &lds[p ^ 1][(wave * 4 + i) * 512]);
        }
        const unsigned short* lp = lds[p];
        f32x4 acc00 = {0.f,0.f,0.f,0.f}, acc01 = {0.f,0.f,0.f,0.f};
        f32x4 acc10 = {0.f,0.f,0.f,0.f}, acc11 = {0.f,0.f,0.f,0.f};
#pragma unroll
        for (int kk = 0; kk < 8; ++kk) {
            short8 a0 = *(const short8*)(lp + (kk * 2 + 0) * 512 + lane * 8);
            short8 a1 = *(const short8*)(lp + (kk * 2 + 1) * 512 + lane * 8);
            acc00 = __builtin_amdgcn_mfma_f32_16x16x32_bf16(a0, bfrag[0][kk], acc00, 0, 0, 0);
            acc10 = __builtin_amdgcn_mfma_f32_16x16x32_bf16(a0, bfrag[1][kk], acc10, 0, 0, 0);
            acc01 = __builtin_amdgcn_mfma_f32_16x16x32_bf16(a1, bfrag[0][kk], acc01, 0, 0, 0);
            acc11 = __builtin_amdgcn_mfma_f32_16x16x32_bf16(a1, bfrag[1][kk], acc11, 0, 0, 0);
        }
        int rb = t * 32 + quad * 4;
        f32x4 v0 = *(const f32x4*)(vs + rb);
        f32x4 v1 = *(const f32x4*)(vs + rb + 16);
        int r0 = t * 32;
        if (r0 >= start && r0 + 32 <= end) {
            // full tile: maskless, max-free
#pragma unroll
            for (int r = 0; r < 4; ++r) {
                float e00 = __builtin_amdgcn_exp2f(acc00[r]);
                float e01 = __builtin_amdgcn_exp2f(acc01[r]);
                float e10 = __builtin_amdgcn_exp2f(acc10[r]);
                float e11 = __builtin_amdgcn_exp2f(acc11[r]);
                den0 += e00 + e01; num0 += e00 * v0[r] + e01 * v1[r];
                den1 += e10 + e11; num1 += e10 * v0[r] + e11 * v1[r];
            }
        } else {
            // boundary tile: per-row masks
#pragma unroll
            for (int r = 0; r < 4; ++r) {
                int ra = rb + r, rb2 = rb + 16 + r;
                bool ma = (ra >= start) && (ra < end);
                bool mb = (rb2 >= start) && (rb2 < end);
                float e00 = ma ? __builtin_amdgcn_exp2f(acc00[r]) : 0.f;
                float e01 = mb ? __builtin_amdgcn_exp2f(acc01[r]) : 0.f;
                float e10 = ma ? __builtin_amdgcn_exp2f(acc10[r]) : 0.f;
                float e11 = mb ? __builtin_amdgcn_exp2f(acc11[r]) : 0.f;
                den0 += e00 + e01; num0 += e00 * v0[r] + e01 * v1[r];
                den1 += e10 + e11; num1 += e10 * v0[r] + e11 * v1[r];
            }
        }
        p ^= 1;
    }

    den0 += __shfl_xor(den0, 16); den0 += __shfl_xor(den0, 32);
    num0 += __shfl_xor(num0, 16); num0 += __shfl_xor(num0, 32);
    den1 += __shfl_xor(den1, 16); den1 += __shfl_xor(den1, 32);
    num1 += __shfl_xor(num1, 16); num1 += __shfl_xor(num1, 32);

    if (quad == 0) {
        size_t base = ((size_t)b * QPTOT + (qp0 + col)) * NSPLIT + chunk;
        partials[base * 2]     = den0;
        partials[base * 2 + 1] = num0;
        size_t base1 = base + (size_t)16 * NSPLIT;
        partials[base1 * 2]     = den1;
        partials[base1 * 2 + 1] = num1;
    }
}

// ---------------- combine: sum NSPLIT (den,num) pairs, divide, scatter -------
__global__ __launch_bounds__(256) void combine_k(
    const float* __restrict__ partials,
    float* __restrict__ out, int Bn)
{
    int gid = blockIdx.x * 256 + threadIdx.x;
    int total = Bn * QPTOT;
    if (gid >= total) return;
    int b = gid / QPTOT, qp = gid - b * QPTOT;
    const float* p = partials + (size_t)gid * NSPLIT * 2;
    float den = 0.f, num = 0.f;
#pragma unroll
    for (int c = 0; c < NSPLIT; ++c) { den += p[c * 2]; num += p[c * 2 + 1]; }
    float val = (den > 0.f) ? (num / den) : 0.f;
    int oidx = -1;
    if (qp < QPT) {
        if (qp < QT_V) oidx = b * QT_V + qp;
    } else if (qp < QPT + QPR) {
        int q = qp - QPT;
        if (q < QR_V) oidx = Bn * QT_V + b * QR_V + q;
    } else {
        int q = qp - QPT - QPR;
        if (q < QO_V) oidx = Bn * (QT_V + QR_V) + b;
    }
    if (oidx >= 0) out[oidx] = val;
}

extern "C" void kernel_launch(void* const* d_in, const int* in_sizes, int n_in,
                              void* d_out, int out_size, void* d_ws, size_t ws_size,
                              hipStream_t stream)
{
    const float* feat = (const float*)d_in[0];
    const int* npts   = (const int*)d_in[1];
    const float* q_t  = (const float*)d_in[2];
    const float* wk_t = (const float*)d_in[3];
    const float* wv_t = (const float*)d_in[4];
    const float* q_r  = (const float*)d_in[5];
    const float* wk_r = (const float*)d_in[6];
    const float* wv_r = (const float*)d_in[7];
    const float* q_o  = (const float*)d_in[8];
    const float* wk_o = (const float*)d_in[9];
    const float* wv_o = (const float*)d_in[10];

    int N  = in_sizes[0] / D_;
    int Bn = in_sizes[1];
    int ntiles = (N + 31) / 32;

    char* ws = (char*)d_ws;
    size_t off = 0;
    unsigned short* WqT = (unsigned short*)(ws + off);
    off += (size_t)QPTOT * D_ * sizeof(unsigned short);
    off = (off + 255) & ~(size_t)255;
    unsigned short* featb = (unsigned short*)(ws + off);
    off += (size_t)ntiles * TILE_US * sizeof(unsigned short);
    off = (off + 255) & ~(size_t)255;
    float* wvsum = (float*)(ws + off);
    off += 3 * D_ * sizeof(float);
    off = (off + 255) & ~(size_t)255;
    float* vsum = (float*)(ws + off);
    off += (size_t)3 * (N + VPAD) * sizeof(float);
    off = (off + 255) & ~(size_t)255;
    float* partials = (float*)(ws + off);
    off += (size_t)Bn * QPTOT * NSPLIT * 2 * sizeof(float);
    (void)ws_size;

    prep_all<<<WQ_BLKS + 1, 256, 0, stream>>>(q_t, wk_t, q_r, wk_r, q_o, wk_o,
                                              wv_t, wv_r, wv_o, WqT, wvsum, vsum, N);
    fuse_feat<<<ntiles, 256, 0, stream>>>(feat, wvsum, featb, vsum, N);

    dim3 grid(NSPLIT, QPTOT / 128, Bn);
    attn_main<<<grid, 256, 0, stream>>>(featb, npts, WqT, vsum, partials, N);

    int total = Bn * QPTOT;
    combine_k<<<(total + 255) / 256, 256, 0, stream>>>(partials, (float*)d_out, Bn);
}

// Round 4
// 189.756 us; speedup vs baseline: 1.6921x; 1.1962x over previous
//
#include <hip/hip_runtime.h>

typedef __attribute__((ext_vector_type(8))) short short8;
typedef __attribute__((ext_vector_type(4))) float f32x4;
typedef unsigned int u32;

#define D_ 256
#define QT_V 3000
#define QR_V 216
#define QO_V 1
#define QPT 3008          // padded head-t rows (94 tiles)
#define QPR 224           // padded head-r rows (7 tiles)
#define QPO 96            // padded head-o rows (3 tiles)
#define QPTOT 3328        // 26 * 128
#define WQ_TILES 104      // 3328/32
#define NSPLIT 8
#define VPAD 32
#define SCALE 0.09016844005556021f   /* log2(e)/16 */
#define TILE_US 8192      /* ushorts per 32x256 bf16 frag-linear tile */
#define PSTRIDE 264       /* padded LDS row stride in ushorts */

__device__ __forceinline__ unsigned short f2bf(float f) {
    union { float f; unsigned int i; } u; u.f = f;
    unsigned int i = u.i + 0x7fffu + ((u.i >> 16) & 1u);
    return (unsigned short)(i >> 16);
}

__device__ __forceinline__ void async_cp16(const unsigned short* g, unsigned short* l) {
    __builtin_amdgcn_global_load_lds((const __attribute__((address_space(1))) u32*)g,
                                     (__attribute__((address_space(3))) u32*)l, 16, 0, 0);
}

// ------------- prep_small: Wk->bf16, wvsum, vsum pads. grid 4 x 256 ---------
__global__ __launch_bounds__(256) void prep_small(
    const float* __restrict__ wk_t, const float* __restrict__ wk_r,
    const float* __restrict__ wk_o,
    const float* __restrict__ wv_t, const float* __restrict__ wv_r,
    const float* __restrict__ wv_o,
    unsigned short* __restrict__ Wkb,
    float* __restrict__ wvsum, float* __restrict__ vsum, int N)
{
    int blk = blockIdx.x, tid = (int)threadIdx.x;
    if (blk < 3) {
        const float* Wk = (blk == 0) ? wk_t : ((blk == 1) ? wk_r : wk_o);
        const float* Wv = (blk == 0) ? wv_t : ((blk == 1) ? wv_r : wv_o);
        // coalesced f32 -> bf16 convert of Wk (256x256)
        for (int i = tid; i < 16384; i += 256) {
            float4 v = ((const float4*)Wk)[i];
            ushort4 o;
            o.x = f2bf(v.x); o.y = f2bf(v.y); o.z = f2bf(v.z); o.w = f2bf(v.w);
            ((ushort4*)(Wkb + (size_t)blk * 65536))[i] = o;
        }
        // wvsum[blk*256 + c] = row-sum of Wv row c
        const float* row = Wv + (size_t)tid * D_;
        float s = 0.f;
        for (int d = 0; d < D_; d += 4) {
            float4 v = *(const float4*)(row + d);
            s += v.x + v.y + v.z + v.w;
        }
        wvsum[blk * 256 + tid] = s;
    } else {
        if (tid < 3 * VPAD) {
            int h = tid / VPAD, i = tid % VPAD;
            vsum[(size_t)h * (N + VPAD) + N + i] = 0.f;
        }
    }
}

// ------------- prep_mid: blocks [0,ntiles) fuse feat; [ntiles,+104) WqT GEMM
__global__ __launch_bounds__(256) void prep_mid(
    const float* __restrict__ feat,
    const float* __restrict__ wvsum,
    const float* __restrict__ q_t, const float* __restrict__ q_r,
    const float* __restrict__ q_o,
    const unsigned short* __restrict__ Wkb,
    unsigned short* __restrict__ featb,
    float* __restrict__ vsum,
    unsigned short* __restrict__ WqT,
    int N, int ntiles)
{
    __shared__ __align__(16) unsigned short lds[32 * PSTRIDE];
    int blk = blockIdx.x, tid = (int)threadIdx.x;
    int srow = tid >> 3, c8 = tid & 7;
    int wave = tid >> 6, lane = tid & 63;
    int col16 = lane & 15, quad = lane >> 4;

    if (blk < ntiles) {
        // ---- fuse_feat: coalesced load f32 -> bf16 LDS + vsum dots ----
        int t = blk;
        int row = t * 32 + srow;
        bool valid = row < N;
        float p0 = 0.f, p1 = 0.f, p2 = 0.f;
#pragma unroll
        for (int i = 0; i < 8; ++i) {
            int col = i * 32 + c8 * 4;
            float4 v;
            if (valid) v = *(const float4*)(feat + (size_t)row * D_ + col);
            else { v.x = v.y = v.z = v.w = 0.f; }
            ushort4 o;
            o.x = f2bf(v.x); o.y = f2bf(v.y); o.z = f2bf(v.z); o.w = f2bf(v.w);
            *(ushort4*)(lds + srow * PSTRIDE + col) = o;
            float4 w0 = *(const float4*)(wvsum + col);
            float4 w1 = *(const float4*)(wvsum + 256 + col);
            float4 w2 = *(const float4*)(wvsum + 512 + col);
            p0 += v.x * w0.x + v.y * w0.y + v.z * w0.z + v.w * w0.w;
            p1 += v.x * w1.x + v.y * w1.y + v.z * w1.z + v.w * w1.w;
            p2 += v.x * w2.x + v.y * w2.y + v.z * w2.z + v.w * w2.w;
        }
        // reduce across the 8 lanes sharing a row (lane bits 0..2 = c8)
        p0 += __shfl_xor(p0, 1); p0 += __shfl_xor(p0, 2); p0 += __shfl_xor(p0, 4);
        p1 += __shfl_xor(p1, 1); p1 += __shfl_xor(p1, 2); p1 += __shfl_xor(p1, 4);
        p2 += __shfl_xor(p2, 1); p2 += __shfl_xor(p2, 2); p2 += __shfl_xor(p2, 4);
        if (c8 == 0 && valid) {
            vsum[0 * (size_t)(N + VPAD) + row] = p0;
            vsum[1 * (size_t)(N + VPAD) + row] = p1;
            vsum[2 * (size_t)(N + VPAD) + row] = p2;
        }
        __syncthreads();
        // ---- swizzle out to frag-linear featb (coalesced 1KB wave stores) --
#pragma unroll
        for (int i = 0; i < 4; ++i) {
            int cmb = wave * 4 + i;
            int kk = cmb >> 1, sub = cmb & 1;
            short8 v = *(const short8*)(lds + (sub * 16 + col16) * PSTRIDE
                                        + quad * 8 + kk * 32);
            *(short8*)(featb + (size_t)t * TILE_US + cmb * 512 + lane * 8) = v;
        }
    } else {
        // ---- WqT GEMM: 32 q-rows x 256 cols, K=256 ----
        int wq = blk - ntiles;
        const float* Q; int nvalid, lq0, outrow, h;
        if (wq < 94)       { Q = q_t; nvalid = QT_V; lq0 = wq * 32;         outrow = lq0;             h = 0; }
        else if (wq < 101) { Q = q_r; nvalid = QR_V; lq0 = (wq - 94) * 32;  outrow = QPT + lq0;       h = 1; }
        else               { Q = q_o; nvalid = QO_V; lq0 = (wq - 101) * 32; outrow = QPT + QPR + lq0; h = 2; }
        int row = lq0 + srow;
        bool valid = row < nvalid;
#pragma unroll
        for (int i = 0; i < 8; ++i) {
            int col = i * 32 + c8 * 4;
            float4 v;
            if (valid) v = *(const float4*)(Q + (size_t)row * D_ + col);
            else { v.x = v.y = v.z = v.w = 0.f; }
            ushort4 o;
            o.x = f2bf(v.x); o.y = f2bf(v.y); o.z = f2bf(v.z); o.w = f2bf(v.w);
            *(ushort4*)(lds + srow * PSTRIDE + col) = o;
        }
        __syncthreads();
        int c0 = wave * 64;
        f32x4 acc[2][4];
#pragma unroll
        for (int mt = 0; mt < 2; ++mt)
#pragma unroll
            for (int nt = 0; nt < 4; ++nt)
                acc[mt][nt] = f32x4{0.f, 0.f, 0.f, 0.f};
        const unsigned short* Wh = Wkb + (size_t)h * 65536;
#pragma unroll
        for (int kk = 0; kk < 8; ++kk) {
            short8 a0 = *(const short8*)(lds + col16 * PSTRIDE + quad * 8 + kk * 32);
            short8 a1 = *(const short8*)(lds + (16 + col16) * PSTRIDE + quad * 8 + kk * 32);
#pragma unroll
            for (int nt = 0; nt < 4; ++nt) {
                short8 bf = *(const short8*)(Wh + (size_t)(c0 + nt * 16 + col16) * D_
                                             + quad * 8 + kk * 32);
                acc[0][nt] = __builtin_amdgcn_mfma_f32_16x16x32_bf16(a0, bf, acc[0][nt], 0, 0, 0);
                acc[1][nt] = __builtin_amdgcn_mfma_f32_16x16x32_bf16(a1, bf, acc[1][nt], 0, 0, 0);
            }
        }
#pragma unroll
        for (int mt = 0; mt < 2; ++mt)
#pragma unroll
            for (int nt = 0; nt < 4; ++nt)
#pragma unroll
                for (int r = 0; r < 4; ++r) {
                    int orow = outrow + mt * 16 + quad * 4 + r;
                    int ocol = c0 + nt * 16 + col16;
                    WqT[(size_t)orow * D_ + ocol] = f2bf(acc[mt][nt][r] * SCALE);
                }
    }
}

// ------------- attn_main: unchanged from round 3 ----------------------------
__global__ __launch_bounds__(256, 4) void attn_main(
    const unsigned short* __restrict__ featb,
    const int* __restrict__ npts,
    const unsigned short* __restrict__ WqT,
    const float* __restrict__ vsum,
    float* __restrict__ partials, int N)
{
    __shared__ __align__(16) unsigned short lds[2][TILE_US];
    int b = blockIdx.z, qblock = blockIdx.y, chunk = blockIdx.x;
    int tid = (int)threadIdx.x;
    int wave = tid >> 6, lane = tid & 63;
    int col = lane & 15, quad = lane >> 4;

    int qp0 = qblock * 128 + wave * 32;
    int h = (qp0 < QPT) ? 0 : ((qp0 < QPT + QPR) ? 1 : 2);
    const float* vs = vsum + (size_t)h * (N + VPAD);

    int start = 0;
#pragma unroll 1
    for (int i = 0; i < b; ++i) start += npts[i];
    int end = start + npts[b];
    if (end > N) end = N;
    if (start < 0) start = 0;
    if (start > end) start = end;
    int bt0 = start >> 5, bt1 = (end + 31) >> 5;
    int ntc = (bt1 - bt0 + NSPLIT - 1) / NSPLIT;
    int ta = bt0 + chunk * ntc;
    int tb = ta + ntc; if (tb > bt1) tb = bt1;

    short8 bfrag[2][8];
#pragma unroll
    for (int qt = 0; qt < 2; ++qt) {
        const unsigned short* wr = WqT + (size_t)(qp0 + qt * 16 + col) * D_ + quad * 8;
#pragma unroll
        for (int kk = 0; kk < 8; ++kk)
            bfrag[qt][kk] = *(const short8*)(wr + kk * 32);
    }

    float den0 = 0.f, num0 = 0.f, den1 = 0.f, num1 = 0.f;
    int p = 0;
    if (ta < tb) {
        const unsigned short* g = featb + (size_t)ta * TILE_US + (wave * 4) * 512 + lane * 8;
#pragma unroll
        for (int i = 0; i < 4; ++i)
            async_cp16(g + i * 512, &lds[0][(wave * 4 + i) * 512]);
    }
#pragma unroll 1
    for (int t = ta; t < tb; ++t) {
        __syncthreads();
        if (t + 1 < tb) {
            const unsigned short* g = featb + (size_t)(t + 1) * TILE_US + (wave * 4) * 512 + lane * 8;
#pragma unroll
            for (int i = 0; i < 4; ++i)
                async_cp16(g + i * 512, &lds[p ^ 1][(wave * 4 + i) * 512]);
        }
        const unsigned short* lp = lds[p];
        f32x4 acc00 = {0.f,0.f,0.f,0.f}, acc01 = {0.f,0.f,0.f,0.f};
        f32x4 acc10 = {0.f,0.f,0.f,0.f}, acc11 = {0.f,0.f,0.f,0.f};
#pragma unroll
        for (int kk = 0; kk < 8; ++kk) {
            short8 a0 = *(const short8*)(lp + (kk * 2 + 0) * 512 + lane * 8);
            short8 a1 = *(const short8*)(lp + (kk * 2 + 1) * 512 + lane * 8);
            acc00 = __builtin_amdgcn_mfma_f32_16x16x32_bf16(a0, bfrag[0][kk], acc00, 0, 0, 0);
            acc10 = __builtin_amdgcn_mfma_f32_16x16x32_bf16(a0, bfrag[1][kk], acc10, 0, 0, 0);
            acc01 = __builtin_amdgcn_mfma_f32_16x16x32_bf16(a1, bfrag[0][kk], acc01, 0, 0, 0);
            acc11 = __builtin_amdgcn_mfma_f32_16x16x32_bf16(a1, bfrag[1][kk], acc11, 0, 0, 0);
        }
        int rb = t * 32 + quad * 4;
        f32x4 v0 = *(const f32x4*)(vs + rb);
        f32x4 v1 = *(const f32x4*)(vs + rb + 16);
        int r0 = t * 32;
        if (r0 >= start && r0 + 32 <= end) {
#pragma unroll
            for (int r = 0; r < 4; ++r) {
                float e00 = __builtin_amdgcn_exp2f(acc00[r]);
                float e01 = __builtin_amdgcn_exp2f(acc01[r]);
                float e10 = __builtin_amdgcn_exp2f(acc10[r]);
                float e11 = __builtin_amdgcn_exp2f(acc11[r]);
                den0 += e00 + e01; num0 += e00 * v0[r] + e01 * v1[r];
                den1 += e10 + e11; num1 += e10 * v0[r] + e11 * v1[r];
            }
        } else {
#pragma unroll
            for (int r = 0; r < 4; ++r) {
                int ra = rb + r, rb2 = rb + 16 + r;
                bool ma = (ra >= start) && (ra < end);
                bool mb = (rb2 >= start) && (rb2 < end);
                float e00 = ma ? __builtin_amdgcn_exp2f(acc00[r]) : 0.f;
                float e01 = mb ? __builtin_amdgcn_exp2f(acc01[r]) : 0.f;
                float e10 = ma ? __builtin_amdgcn_exp2f(acc10[r]) : 0.f;
                float e11 = mb ? __builtin_amdgcn_exp2f(acc11[r]) : 0.f;
                den0 += e00 + e01; num0 += e00 * v0[r] + e01 * v1[r];
                den1 += e10 + e11; num1 += e10 * v0[r] + e11 * v1[r];
            }
        }
        p ^= 1;
    }

    den0 += __shfl_xor(den0, 16); den0 += __shfl_xor(den0, 32);
    num0 += __shfl_xor(num0, 16); num0 += __shfl_xor(num0, 32);
    den1 += __shfl_xor(den1, 16); den1 += __shfl_xor(den1, 32);
    num1 += __shfl_xor(num1, 16); num1 += __shfl_xor(num1, 32);

    if (quad == 0) {
        size_t base = ((size_t)b * QPTOT + (qp0 + col)) * NSPLIT + chunk;
        partials[base * 2]     = den0;
        partials[base * 2 + 1] = num0;
        size_t base1 = base + (size_t)16 * NSPLIT;
        partials[base1 * 2]     = den1;
        partials[base1 * 2 + 1] = num1;
    }
}

// ------------- combine: unchanged ------------------------------------------
__global__ __launch_bounds__(256) void combine_k(
    const float* __restrict__ partials,
    float* __restrict__ out, int Bn)
{
    int gid = blockIdx.x * 256 + threadIdx.x;
    int total = Bn * QPTOT;
    if (gid >= total) return;
    int b = gid / QPTOT, qp = gid - b * QPTOT;
    const float* p = partials + (size_t)gid * NSPLIT * 2;
    float den = 0.f, num = 0.f;
#pragma unroll
    for (int c = 0; c < NSPLIT; ++c) { den += p[c * 2]; num += p[c * 2 + 1]; }
    float val = (den > 0.f) ? (num / den) : 0.f;
    int oidx = -1;
    if (qp < QPT) {
        if (qp < QT_V) oidx = b * QT_V + qp;
    } else if (qp < QPT + QPR) {
        int q = qp - QPT;
        if (q < QR_V) oidx = Bn * QT_V + b * QR_V + q;
    } else {
        int q = qp - QPT - QPR;
        if (q < QO_V) oidx = Bn * (QT_V + QR_V) + b;
    }
    if (oidx >= 0) out[oidx] = val;
}

extern "C" void kernel_launch(void* const* d_in, const int* in_sizes, int n_in,
                              void* d_out, int out_size, void* d_ws, size_t ws_size,
                              hipStream_t stream)
{
    const float* feat = (const float*)d_in[0];
    const int* npts   = (const int*)d_in[1];
    const float* q_t  = (const float*)d_in[2];
    const float* wk_t = (const float*)d_in[3];
    const float* wv_t = (const float*)d_in[4];
    const float* q_r  = (const float*)d_in[5];
    const float* wk_r = (const float*)d_in[6];
    const float* wv_r = (const float*)d_in[7];
    const float* q_o  = (const float*)d_in[8];
    const float* wk_o = (const float*)d_in[9];
    const float* wv_o = (const float*)d_in[10];

    int N  = in_sizes[0] / D_;
    int Bn = in_sizes[1];
    int ntiles = (N + 31) / 32;

    char* ws = (char*)d_ws;
    size_t off = 0;
    unsigned short* WqT = (unsigned short*)(ws + off);
    off += (size_t)QPTOT * D_ * sizeof(unsigned short);
    off = (off + 255) & ~(size_t)255;
    unsigned short* featb = (unsigned short*)(ws + off);
    off += (size_t)ntiles * TILE_US * sizeof(unsigned short);
    off = (off + 255) & ~(size_t)255;
    unsigned short* Wkb = (unsigned short*)(ws + off);
    off += (size_t)3 * 65536 * sizeof(unsigned short);
    off = (off + 255) & ~(size_t)255;
    float* wvsum = (float*)(ws + off);
    off += 3 * D_ * sizeof(float);
    off = (off + 255) & ~(size_t)255;
    float* vsum = (float*)(ws + off);
    off += (size_t)3 * (N + VPAD) * sizeof(float);
    off = (off + 255) & ~(size_t)255;
    float* partials = (float*)(ws + off);
    off += (size_t)Bn * QPTOT * NSPLIT * 2 * sizeof(float);
    (void)ws_size;

    prep_small<<<4, 256, 0, stream>>>(wk_t, wk_r, wk_o, wv_t, wv_r, wv_o,
                                      Wkb, wvsum, vsum, N);
    prep_mid<<<ntiles + WQ_TILES, 256, 0, stream>>>(feat, wvsum, q_t, q_r, q_o,
                                                    Wkb, featb, vsum, WqT, N, ntiles);

    dim3 grid(NSPLIT, QPTOT / 128, Bn);
    attn_main<<<grid, 256, 0, stream>>>(featb, npts, WqT, vsum, partials, N);

    int total = Bn * QPTOT;
    combine_k<<<(total + 255) / 256, 256, 0, stream>>>(partials, (float*)d_out, Bn);
}